// Round 1
// baseline (271.939 us; speedup 1.0000x reference)
//
#include <hip/hip_runtime.h>

#define NC 640
#define NQ 2048
#define NW 64
#define CH 16

// KC = log2(e)/EPS, EPS = 0.05
constexpr float KC = 28.853900817779268f;

static __device__ __forceinline__ float hrcp(float x) { return __builtin_amdgcn_rcpf(x); }

// ---------------------------------------------------------------------------
// Feature kernel: per (n, c) compute the 5 patch means of the 5x5 map, then
// block-reduce over c to get per-(n,p) mean and inv-norm of the centered
// feature; write both uncentered (k=0..4) and centered-normalized (k=5..9).
// trans=0: layout [n][c][10]           (query)
// trans=1: layout [c][k/2][64][2]      (proto, for coalesced+conflict-free use)
// ---------------------------------------------------------------------------
__global__ __launch_bounds__(640) void feat_kernel(const float* __restrict__ x,
                                                   float* __restrict__ outf,
                                                   int trans)
{
  const int n = blockIdx.x;
  const int c = threadIdx.x;          // 0..639, one channel per thread
  const float* px = x + ((size_t)n * NC + c) * 25;
  float v[25];
#pragma unroll
  for (int i = 0; i < 25; i++) v[i] = px[i];

  float f[5];
  {
    float lt = 0.f, rt = 0.f, mid = 0.f, lb = 0.f, rb = 0.f;
#pragma unroll
    for (int i = 0; i < 3; i++)
#pragma unroll
      for (int j = 0; j < 3; j++) {
        lt += v[i * 5 + j];
        rt += v[(i + 2) * 5 + j];
        lb += v[i * 5 + (j + 2)];
        rb += v[(i + 2) * 5 + (j + 2)];
      }
#pragma unroll
    for (int i = 1; i < 5; i++)
#pragma unroll
      for (int j = 1; j < 5; j++) mid += v[i * 5 + j];
    f[0] = lt * (1.f / 9.f);
    f[1] = rt * (1.f / 9.f);
    f[2] = mid * (1.f / 16.f);
    f[3] = lb * (1.f / 9.f);
    f[4] = rb * (1.f / 9.f);
  }

  // block reduction over c: sum f[p] and f[p]^2
  float s[10];
#pragma unroll
  for (int p = 0; p < 5; p++) { s[p] = f[p]; s[5 + p] = f[p] * f[p]; }
#pragma unroll
  for (int off = 32; off > 0; off >>= 1)
#pragma unroll
    for (int k = 0; k < 10; k++) s[k] += __shfl_xor(s[k], off);

  __shared__ float wred[10][10];
  __shared__ float bc[10];
  const int lane = c & 63;
  const int wv = c >> 6;
  if (lane == 0) {
#pragma unroll
    for (int k = 0; k < 10; k++) wred[wv][k] = s[k];
  }
  __syncthreads();
  if (c < 5) {
    float s1 = 0.f, s2 = 0.f;
#pragma unroll
    for (int w = 0; w < 10; w++) { s1 += wred[w][c]; s2 += wred[w][5 + c]; }
    float mu = s1 * (1.0f / NC);
    // ||f - mu||^2 = sum f^2 - NC*mu^2
    float n2 = fmaxf(s2 - (float)NC * mu * mu, 0.0f);
    float nrm = fmaxf(sqrtf(n2), 1e-8f);
    bc[c] = mu;
    bc[5 + c] = 1.0f / nrm;
  }
  __syncthreads();

#pragma unroll
  for (int p = 0; p < 5; p++) {
    float fv = f[p];
    float cf = (fv - bc[p]) * bc[5 + p];
    if (trans) {
      // packed-pair layout: idx(c,k,n) = (c*5 + k/2)*128 + n*2 + (k&1)
      int k0 = p;
      int k1 = 5 + p;
      outf[((size_t)c * 5 + (k0 >> 1)) * 128 + n * 2 + (k0 & 1)] = fv;
      outf[((size_t)c * 5 + (k1 >> 1)) * 128 + n * 2 + (k1 & 1)] = cf;
    } else {
      outf[((size_t)n * NC + c) * 10 + p] = fv;
      outf[((size_t)n * NC + c) * 10 + 5 + p] = cf;
    }
  }
}

// ---------------------------------------------------------------------------
// Fused sim + Sinkhorn kernel.
// Block = 256 threads = 4 waves; wave <-> one query m; lane <-> proto w.
// Phase 1: loop c in chunks of CH; stage proto chunk ([c][j][w][2], 40KB)
//          into LDS; accumulate dot[5] (uncentered) and sim[25] (centered-
//          normalized) in registers.
// Phase 2: per-thread linear-domain Sinkhorn (100 iters) fully in registers.
// ---------------------------------------------------------------------------
__global__ __launch_bounds__(256) void sinkhorn_kernel(const float* __restrict__ fq,
                                                       const float* __restrict__ fpt,
                                                       float* __restrict__ out)
{
  __shared__ float ldsP[CH * 5 * 128];  // 40 KB: [cc][j][w*2]
  const int tid = threadIdx.x;
  const int lane = tid & 63;
  const int wv = tid >> 6;
  const int m = blockIdx.x * 4 + wv;

  float dot[5] = {0.f, 0.f, 0.f, 0.f, 0.f};
  float sm[25];
#pragma unroll
  for (int i = 0; i < 25; i++) sm[i] = 0.f;

  const float* qb = fq + (size_t)m * (NC * 10);

  for (int c0 = 0; c0 < NC; c0 += CH) {
    __syncthreads();  // protect previous chunk's readers
    // cooperative stage: CH*640 floats = 2560 float4, 10 per thread
    const float4* src = (const float4*)(fpt + (size_t)c0 * 640);
    float4* dst = (float4*)ldsP;
#pragma unroll
    for (int i = 0; i < 10; i++) dst[tid + i * 256] = src[tid + i * 256];
    __syncthreads();

#pragma unroll
    for (int cc = 0; cc < CH; cc++) {
      float p0[10], qa[10];
#pragma unroll
      for (int j = 0; j < 5; j++) {
        float2 t = *(const float2*)&ldsP[(cc * 5 + j) * 128 + lane * 2];
        p0[2 * j] = t.x;
        p0[2 * j + 1] = t.y;
      }
#pragma unroll
      for (int j = 0; j < 5; j++) {
        float2 t = *(const float2*)(qb + (size_t)(c0 + cc) * 10 + 2 * j);
        qa[2 * j] = t.x;
        qa[2 * j + 1] = t.y;
      }
#pragma unroll
      for (int p = 0; p < 5; p++) dot[p] = fmaf(qa[p], p0[p], dot[p]);
#pragma unroll
      for (int i = 0; i < 5; i++)
#pragma unroll
        for (int j = 0; j < 5; j++)
          sm[i * 5 + j] = fmaf(qa[5 + i], p0[5 + j], sm[i * 5 + j]);
    }
  }

  // weights: a == b == normalize(relu(dot) + 0.001 + 1e-5) to sum 5
  float a[5];
  float suma = 0.f;
#pragma unroll
  for (int p = 0; p < 5; p++) {
    a[p] = fmaxf(dot[p], 0.f) + 0.00101f;
    suma += a[p];
  }
  float rs = 5.0f / suma;
#pragma unroll
  for (int p = 0; p < 5; p++) a[p] *= rs;

  // K = exp(-(1-sim)/eps) = exp2((sim-1)*KC)
  float Km[25];
#pragma unroll
  for (int i = 0; i < 25; i++) Km[i] = __builtin_amdgcn_exp2f((sm[i] - 1.0f) * KC);

  // linear-domain Sinkhorn: u = a/(K v), v = b/(K^T u); init f=g=0 -> u=v=1
  float u[5], v[5];
#pragma unroll
  for (int p = 0; p < 5; p++) { u[p] = 1.f; v[p] = 1.f; }
  for (int it = 0; it < 100; ++it) {
#pragma unroll
    for (int i = 0; i < 5; i++) {
      float kv = Km[i * 5] * v[0];
#pragma unroll
      for (int j = 1; j < 5; j++) kv = fmaf(Km[i * 5 + j], v[j], kv);
      u[i] = a[i] * hrcp(kv);
    }
#pragma unroll
    for (int j = 0; j < 5; j++) {
      float ku = Km[j] * u[0];
#pragma unroll
      for (int i = 1; i < 5; i++) ku = fmaf(Km[i * 5 + j], u[i], ku);
      v[j] = a[j] * hrcp(ku);
    }
  }

  // logits = sum_ij sim * (u_i K_ij v_j) * (TEMP/P = 2.5)
  float acc = 0.f;
#pragma unroll
  for (int i = 0; i < 5; i++)
#pragma unroll
    for (int j = 0; j < 5; j++)
      acc += u[i] * Km[i * 5 + j] * v[j] * sm[i * 5 + j];

  out[(size_t)m * 64 + lane] = acc * 2.5f;
}

extern "C" void kernel_launch(void* const* d_in, const int* in_sizes, int n_in,
                              void* d_out, int out_size, void* d_ws, size_t ws_size,
                              hipStream_t stream) {
  const float* proto = (const float*)d_in[0];  // (1,64,640,5,5)
  const float* query = (const float*)d_in[1];  // (2048,640,5,5)
  float* out = (float*)d_out;                  // (2048,64) f32

  // workspace: feat_q = 2048*640*10 f32 (52.4MB), feat_pt = 640*5*128 f32 (1.6MB)
  float* feat_q = (float*)d_ws;
  float* feat_pt = feat_q + (size_t)NQ * NC * 10;

  feat_kernel<<<NW, NC, 0, stream>>>(proto, feat_pt, 1);
  feat_kernel<<<NQ, NC, 0, stream>>>(query, feat_q, 0);
  sinkhorn_kernel<<<NQ / 4, 256, 0, stream>>>(feat_q, feat_pt, out);
}

// Round 2
// 209.168 us; speedup vs baseline: 1.3001x; 1.3001x over previous
//
#include <hip/hip_runtime.h>

#define NC 640
#define NQ 2048
#define NW 64
#define CH 8
#define NCH (NC / CH)

// KC = log2(e)/EPS, EPS = 0.05
constexpr float KC = 28.853900817779268f;

typedef __attribute__((address_space(3))) void* lds_ptr_t;
typedef const __attribute__((address_space(1))) void* glb_ptr_t;

static __device__ __forceinline__ float hrcp(float x) { return __builtin_amdgcn_rcpf(x); }

// ---------------------------------------------------------------------------
// Feature kernel (unchanged from R1): per (n,c) 5 patch means, block reduce
// for per-(n,p) mean + inv-norm; write uncentered (k=0..4) and centered-
// normalized (k=5..9).
// trans=0: [n][c][10] (query)   trans=1: [c][k/2][64][2] (proto)
// ---------------------------------------------------------------------------
__global__ __launch_bounds__(640) void feat_kernel(const float* __restrict__ x,
                                                   float* __restrict__ outf,
                                                   int trans)
{
  const int n = blockIdx.x;
  const int c = threadIdx.x;
  const float* px = x + ((size_t)n * NC + c) * 25;
  float v[25];
#pragma unroll
  for (int i = 0; i < 25; i++) v[i] = px[i];

  float f[5];
  {
    float lt = 0.f, rt = 0.f, mid = 0.f, lb = 0.f, rb = 0.f;
#pragma unroll
    for (int i = 0; i < 3; i++)
#pragma unroll
      for (int j = 0; j < 3; j++) {
        lt += v[i * 5 + j];
        rt += v[(i + 2) * 5 + j];
        lb += v[i * 5 + (j + 2)];
        rb += v[(i + 2) * 5 + (j + 2)];
      }
#pragma unroll
    for (int i = 1; i < 5; i++)
#pragma unroll
      for (int j = 1; j < 5; j++) mid += v[i * 5 + j];
    f[0] = lt * (1.f / 9.f);
    f[1] = rt * (1.f / 9.f);
    f[2] = mid * (1.f / 16.f);
    f[3] = lb * (1.f / 9.f);
    f[4] = rb * (1.f / 9.f);
  }

  float s[10];
#pragma unroll
  for (int p = 0; p < 5; p++) { s[p] = f[p]; s[5 + p] = f[p] * f[p]; }
#pragma unroll
  for (int off = 32; off > 0; off >>= 1)
#pragma unroll
    for (int k = 0; k < 10; k++) s[k] += __shfl_xor(s[k], off);

  __shared__ float wred[10][10];
  __shared__ float bc[10];
  const int lane = c & 63;
  const int wv = c >> 6;
  if (lane == 0) {
#pragma unroll
    for (int k = 0; k < 10; k++) wred[wv][k] = s[k];
  }
  __syncthreads();
  if (c < 5) {
    float s1 = 0.f, s2 = 0.f;
#pragma unroll
    for (int w = 0; w < 10; w++) { s1 += wred[w][c]; s2 += wred[w][5 + c]; }
    float mu = s1 * (1.0f / NC);
    float n2 = fmaxf(s2 - (float)NC * mu * mu, 0.0f);
    float nrm = fmaxf(sqrtf(n2), 1e-8f);
    bc[c] = mu;
    bc[5 + c] = 1.0f / nrm;
  }
  __syncthreads();

#pragma unroll
  for (int p = 0; p < 5; p++) {
    float fv = f[p];
    float cf = (fv - bc[p]) * bc[5 + p];
    if (trans) {
      int k0 = p;
      int k1 = 5 + p;
      outf[((size_t)c * 5 + (k0 >> 1)) * 128 + n * 2 + (k0 & 1)] = fv;
      outf[((size_t)c * 5 + (k1 >> 1)) * 128 + n * 2 + (k1 & 1)] = cf;
    } else {
      outf[((size_t)n * NC + c) * 10 + p] = fv;
      outf[((size_t)n * NC + c) * 10 + 5 + p] = cf;
    }
  }
}

// ---------------------------------------------------------------------------
// Fused sim + Sinkhorn kernel, double-buffered async staging.
// Block = 256 threads = 4 waves; wave <-> query m; lane <-> proto w.
// Per chunk (CH=8 channels): proto 20KB + per-wave query 320B staged via
// global_load_lds (async); counted vmcnt(6) keeps next chunk's 6 loads in
// flight across the barrier. Inner loop reads only LDS.
// ---------------------------------------------------------------------------
__global__ __launch_bounds__(256) void sinkhorn_kernel(const float* __restrict__ fq,
                                                       const float* __restrict__ fpt,
                                                       float* __restrict__ out)
{
  __shared__ float ldsP[2][CH * 5 * 128];  // 2 x 20 KB  [cc][j][w*2]
  __shared__ float ldsQ[2][4][CH * 10];    // 2 x 1.25 KB [wave][cc*10+k]
  const int tid = threadIdx.x;
  const int lane = tid & 63;
  const int wv = tid >> 6;
  const int m = blockIdx.x * 4 + wv;
  const float* __restrict__ qrow = fq + (size_t)m * (NC * 10);

  float dot[5] = {0.f, 0.f, 0.f, 0.f, 0.f};
  float sm[25];
#pragma unroll
  for (int i = 0; i < 25; i++) sm[i] = 0.f;

  // stage chunk t into buffer b: 5 proto loads + 1 query load per wave (async)
  auto stage = [&](int t, int b) {
    const float* ps = fpt + (size_t)t * (CH * 640);
#pragma unroll
    for (int i = 0; i < 5; i++) {
      int off = (wv * 5 + i) * 256 + lane * 4;  // floats; lane*16B contiguous
      __builtin_amdgcn_global_load_lds((glb_ptr_t)(ps + off),
                                       (lds_ptr_t)(&ldsP[b][off]), 16, 0, 0);
    }
    if (lane < 20) {
      __builtin_amdgcn_global_load_lds((glb_ptr_t)(qrow + (size_t)t * (CH * 10) + lane * 4),
                                       (lds_ptr_t)(&ldsQ[b][wv][lane * 4]), 16, 0, 0);
    }
  };

  stage(0, 0);
  for (int t = 0; t < NCH; ++t) {
    const int b = t & 1;
    if (t + 1 < NCH) {
      stage(t + 1, 1 - b);  // 6 more in flight -> 12 outstanding
      asm volatile("s_waitcnt vmcnt(6)" ::: "memory");  // chunk t landed
    } else {
      asm volatile("s_waitcnt vmcnt(0)" ::: "memory");
    }
    __builtin_amdgcn_sched_barrier(0);
    __builtin_amdgcn_s_barrier();  // all waves' chunk-t stages visible

    const float* Pb = ldsP[b];
    const float* Qb = ldsQ[b][wv];
#pragma unroll
    for (int cc = 0; cc < CH; cc++) {
      float p0[10], qa[10];
#pragma unroll
      for (int j = 0; j < 5; j++) {
        float2 tp = *(const float2*)&Pb[(cc * 5 + j) * 128 + lane * 2];
        p0[2 * j] = tp.x;
        p0[2 * j + 1] = tp.y;
      }
#pragma unroll
      for (int j = 0; j < 5; j++) {
        float2 tq = *(const float2*)&Qb[cc * 10 + 2 * j];
        qa[2 * j] = tq.x;
        qa[2 * j + 1] = tq.y;
      }
#pragma unroll
      for (int p = 0; p < 5; p++) dot[p] = fmaf(qa[p], p0[p], dot[p]);
#pragma unroll
      for (int i = 0; i < 5; i++)
#pragma unroll
        for (int j = 0; j < 5; j++)
          sm[i * 5 + j] = fmaf(qa[5 + i], p0[5 + j], sm[i * 5 + j]);
    }
    __builtin_amdgcn_sched_barrier(0);
    __builtin_amdgcn_s_barrier();  // buf b free for restage next iter
  }

  // weights: a == b == normalize(relu(dot) + 0.001 + 1e-5) to sum 5
  float a[5];
  float suma = 0.f;
#pragma unroll
  for (int p = 0; p < 5; p++) {
    a[p] = fmaxf(dot[p], 0.f) + 0.00101f;
    suma += a[p];
  }
  float rs = 5.0f / suma;
#pragma unroll
  for (int p = 0; p < 5; p++) a[p] *= rs;

  // K = exp(-(1-sim)/eps) = exp2((sim-1)*KC)
  float Km[25];
#pragma unroll
  for (int i = 0; i < 25; i++) Km[i] = __builtin_amdgcn_exp2f((sm[i] - 1.0f) * KC);

  // linear-domain Sinkhorn: u = a/(K v), v = b/(K^T u)
  float u[5], v[5];
#pragma unroll
  for (int p = 0; p < 5; p++) { u[p] = 1.f; v[p] = 1.f; }
  for (int it = 0; it < 100; ++it) {
#pragma unroll
    for (int i = 0; i < 5; i++) {
      float kv = Km[i * 5] * v[0];
#pragma unroll
      for (int j = 1; j < 5; j++) kv = fmaf(Km[i * 5 + j], v[j], kv);
      u[i] = a[i] * hrcp(kv);
    }
#pragma unroll
    for (int j = 0; j < 5; j++) {
      float ku = Km[j] * u[0];
#pragma unroll
      for (int i = 1; i < 5; i++) ku = fmaf(Km[i * 5 + j], u[i], ku);
      v[j] = a[j] * hrcp(ku);
    }
  }

  float acc = 0.f;
#pragma unroll
  for (int i = 0; i < 5; i++)
#pragma unroll
    for (int j = 0; j < 5; j++)
      acc += u[i] * Km[i * 5 + j] * v[j] * sm[i * 5 + j];

  out[(size_t)m * 64 + lane] = acc * 2.5f;
}

extern "C" void kernel_launch(void* const* d_in, const int* in_sizes, int n_in,
                              void* d_out, int out_size, void* d_ws, size_t ws_size,
                              hipStream_t stream) {
  const float* proto = (const float*)d_in[0];  // (1,64,640,5,5)
  const float* query = (const float*)d_in[1];  // (2048,640,5,5)
  float* out = (float*)d_out;                  // (2048,64) f32

  float* feat_q = (float*)d_ws;                       // 52.4 MB
  float* feat_pt = feat_q + (size_t)NQ * NC * 10;     // 1.6 MB

  feat_kernel<<<NW, NC, 0, stream>>>(proto, feat_pt, 1);
  feat_kernel<<<NQ, NC, 0, stream>>>(query, feat_q, 0);
  sinkhorn_kernel<<<NQ / 4, 256, 0, stream>>>(feat_q, feat_pt, out);
}

// Round 4
// 157.618 us; speedup vs baseline: 1.7253x; 1.3271x over previous
//
#include <hip/hip_runtime.h>

#define NC 640
#define NQ 2048
#define NW 64
#define CH 8
#define NCH (NC / CH)

typedef unsigned short u16;
typedef unsigned int u32;
typedef __attribute__((ext_vector_type(8))) short short8;
typedef __attribute__((ext_vector_type(4))) float f32x4;
typedef __attribute__((address_space(3))) void* lds_ptr_t;
typedef const __attribute__((address_space(1))) void* glb_ptr_t;

// KC = log2(e)/EPS, EPS = 0.05
constexpr float KC = 28.853900817779268f;

static __device__ __forceinline__ float hrcp(float x) { return __builtin_amdgcn_rcpf(x); }
static __device__ __forceinline__ u16 f2bf(float f) {
  u32 u = __float_as_uint(f);
  u += 0x7FFF + ((u >> 16) & 1);
  return (u16)(u >> 16);
}
static __device__ __forceinline__ float bf2f(u16 h) {
  return __uint_as_float(((u32)h) << 16);
}

// ---------------------------------------------------------------------------
// Shared Sinkhorn core: given sim[25] + dot[5] in fp32, produce the logit.
// ---------------------------------------------------------------------------
static __device__ __forceinline__ float sinkhorn_core(const float* sm, const float* dot) {
  float a[5];
  float suma = 0.f;
#pragma unroll
  for (int p = 0; p < 5; p++) {
    a[p] = fmaxf(dot[p], 0.f) + 0.00101f;
    suma += a[p];
  }
  float rs = 5.0f / suma;
#pragma unroll
  for (int p = 0; p < 5; p++) a[p] *= rs;

  float Km[25];
#pragma unroll
  for (int i = 0; i < 25; i++) Km[i] = __builtin_amdgcn_exp2f((sm[i] - 1.0f) * KC);

  float u[5], v[5];
#pragma unroll
  for (int p = 0; p < 5; p++) { u[p] = 1.f; v[p] = 1.f; }
  for (int it = 0; it < 100; ++it) {
#pragma unroll
    for (int i = 0; i < 5; i++) {
      float kv = Km[i * 5] * v[0];
#pragma unroll
      for (int j = 1; j < 5; j++) kv = fmaf(Km[i * 5 + j], v[j], kv);
      u[i] = a[i] * hrcp(kv);
    }
#pragma unroll
    for (int j = 0; j < 5; j++) {
      float ku = Km[j] * u[0];
#pragma unroll
      for (int i = 1; i < 5; i++) ku = fmaf(Km[i * 5 + j], u[i], ku);
      v[j] = a[j] * hrcp(ku);
    }
  }

  float acc = 0.f;
#pragma unroll
  for (int i = 0; i < 5; i++)
#pragma unroll
    for (int j = 0; j < 5; j++)
      acc += u[i] * Km[i * 5 + j] * v[j] * sm[i * 5 + j];
  return acc * 2.5f;
}

// ---------------------------------------------------------------------------
// Per-thread patch-mean + block stats helper (640 threads, one channel each).
// Returns f[5] patch means; bc[10] = {mu[5], invnorm[5]}.
// ---------------------------------------------------------------------------
static __device__ __forceinline__ void feat_compute(const float* v, float* f,
                                                    float* bc, float (*wred)[10],
                                                    int t) {
  {
    float lt = 0.f, rt = 0.f, mid = 0.f, lb = 0.f, rb = 0.f;
#pragma unroll
    for (int i = 0; i < 3; i++)
#pragma unroll
      for (int j = 0; j < 3; j++) {
        lt += v[i * 5 + j];
        rt += v[(i + 2) * 5 + j];
        lb += v[i * 5 + (j + 2)];
        rb += v[(i + 2) * 5 + (j + 2)];
      }
#pragma unroll
    for (int i = 1; i < 5; i++)
#pragma unroll
      for (int j = 1; j < 5; j++) mid += v[i * 5 + j];
    f[0] = lt * (1.f / 9.f);
    f[1] = rt * (1.f / 9.f);
    f[2] = mid * (1.f / 16.f);
    f[3] = lb * (1.f / 9.f);
    f[4] = rb * (1.f / 9.f);
  }
  float s[10];
#pragma unroll
  for (int p = 0; p < 5; p++) { s[p] = f[p]; s[5 + p] = f[p] * f[p]; }
#pragma unroll
  for (int off = 32; off > 0; off >>= 1)
#pragma unroll
    for (int k = 0; k < 10; k++) s[k] += __shfl_xor(s[k], off);
  const int lane = t & 63;
  const int wv = t >> 6;
  if (lane == 0) {
#pragma unroll
    for (int k = 0; k < 10; k++) wred[wv][k] = s[k];
  }
  __syncthreads();
  if (t < 5) {
    float s1 = 0.f, s2 = 0.f;
#pragma unroll
    for (int w = 0; w < 10; w++) { s1 += wred[w][t]; s2 += wred[w][5 + t]; }
    float mu = s1 * (1.0f / NC);
    float n2 = fmaxf(s2 - (float)NC * mu * mu, 0.0f);
    float nrm = fmaxf(sqrtf(n2), 1e-8f);
    bc[t] = mu;
    bc[5 + t] = 1.0f / nrm;
  }
  __syncthreads();
}

// ===========================================================================
// MAIN PATH: split-bf16 features -> 3-pass MFMA GEMM -> packed f32 -> sink
// ===========================================================================

// Feature kernel writing hi/lo bf16 rows [n*10+k][640]:
// k<5 = centered-normalized (sim operand), k>=5 = raw mean (weight operand).
__global__ __launch_bounds__(640) void feat_hl_kernel(const float* __restrict__ x,
                                                      u16* __restrict__ outh,
                                                      u16* __restrict__ outl)
{
  __shared__ float lin[16000];
  __shared__ float wred[10][10];
  __shared__ float bc[10];
  const int n = blockIdx.x;
  const int t = threadIdx.x;

  {
    const float4* src = (const float4*)(x + (size_t)n * 16000);
    float4* dst = (float4*)lin;
#pragma unroll
    for (int i = 0; i < 6; i++) dst[t + i * 640] = src[t + i * 640];
    if (t < 160) dst[t + 3840] = src[t + 3840];
  }
  __syncthreads();

  float f[5];
  feat_compute(lin + t * 25, f, bc, wred, t);

  float* lout = lin;  // reuse
#pragma unroll
  for (int p = 0; p < 5; p++) {
    float fv = f[p];
    lout[p * 640 + t] = (fv - bc[p]) * bc[5 + p];
    lout[(5 + p) * 640 + t] = fv;
  }
  __syncthreads();

  u32* outhu = (u32*)outh;
  u32* outlu = (u32*)outl;
#pragma unroll
  for (int i = 0; i < 5; i++) {
    int j = t + i * 640;
    int k = j / 320;
    int cp = j - k * 320;
    float f0 = lout[k * 640 + cp * 2];
    float f1 = lout[k * 640 + cp * 2 + 1];
    u16 h0 = f2bf(f0), h1 = f2bf(f1);
    float l0 = f0 - bf2f(h0);
    float l1 = f1 - bf2f(h1);
    size_t o = ((size_t)n * 10 + k) * 320 + cp;
    outhu[o] = (u32)h0 | ((u32)h1 << 16);
    outlu[o] = (u32)f2bf(l0) | ((u32)f2bf(l1) << 16);
  }
}

// 3-pass split-bf16 GEMM: acc += Ah*Bh + Ah*Bl + Al*Bh (fp32 acc).
// 128x128 tile, BK=32, 4 waves 2x2, double-buffered global_load_lds,
// counted vmcnt(8). Epilogue writes only the needed 30 f32 per (m,w) pair.
__global__ __launch_bounds__(256) void gemm3_kernel(const u16* __restrict__ Ah,
                                                    const u16* __restrict__ Al,
                                                    const u16* __restrict__ Bh,
                                                    const u16* __restrict__ Bl,
                                                    float* __restrict__ packed)
{
  __shared__ u16 ldsAh[2][128 * 32];
  __shared__ u16 ldsAl[2][128 * 32];
  __shared__ u16 ldsBh[2][128 * 32];
  __shared__ u16 ldsBl[2][128 * 32];
  const int bid = blockIdx.x;
  const int tsw = (bid & 7) * 100 + (bid >> 3);  // bijective over 800
  const int bm = tsw / 5;    // 0..159; neighbors share A-panel on same XCD
  const int bn = tsw % 5;    // 0..4
  const int row0 = bm * 128;
  const int col0 = bn * 128;
  const int tid = threadIdx.x;
  const int lane = tid & 63;
  const int w = tid >> 6;
  const int wr = w >> 1;
  const int wc = w & 1;

  f32x4 acc[4][4];
#pragma unroll
  for (int m = 0; m < 4; m++)
#pragma unroll
    for (int n = 0; n < 4; n++) acc[m][n] = (f32x4){0.f, 0.f, 0.f, 0.f};

  auto stage = [&](int kt, int b) {
    const int k0 = kt * 32;
    const int ch = tid & 3;
    const int rr = tid >> 2;
#pragma unroll
    for (int i = 0; i < 2; i++) {
      const int r = rr + 64 * i;
      const size_t goA = (size_t)(row0 + r) * 640 + k0 + ch * 8;
      const size_t goB = (size_t)(col0 + r) * 640 + k0 + ch * 8;
      const int lo = r * 32 + ch * 8;
      __builtin_amdgcn_global_load_lds((glb_ptr_t)(Ah + goA), (lds_ptr_t)(&ldsAh[b][lo]), 16, 0, 0);
      __builtin_amdgcn_global_load_lds((glb_ptr_t)(Al + goA), (lds_ptr_t)(&ldsAl[b][lo]), 16, 0, 0);
      __builtin_amdgcn_global_load_lds((glb_ptr_t)(Bh + goB), (lds_ptr_t)(&ldsBh[b][lo]), 16, 0, 0);
      __builtin_amdgcn_global_load_lds((glb_ptr_t)(Bl + goB), (lds_ptr_t)(&ldsBl[b][lo]), 16, 0, 0);
    }
  };

  stage(0, 0);
  for (int kt = 0; kt < 20; ++kt) {
    const int b = kt & 1;
    if (kt < 19) {
      stage(kt + 1, b ^ 1);
      asm volatile("s_waitcnt vmcnt(8)" ::: "memory");
    } else {
      asm volatile("s_waitcnt vmcnt(0)" ::: "memory");
    }
    __builtin_amdgcn_sched_barrier(0);
    __builtin_amdgcn_s_barrier();

    short8 ah[4], al[4], bh[4], bl[4];
    const int ko = (lane >> 4) * 8;
#pragma unroll
    for (int m = 0; m < 4; m++) {
      const int ro = (wr * 64 + m * 16 + (lane & 15)) * 32 + ko;
      ah[m] = *(const short8*)&ldsAh[b][ro];
      al[m] = *(const short8*)&ldsAl[b][ro];
    }
#pragma unroll
    for (int n = 0; n < 4; n++) {
      const int ro = (wc * 64 + n * 16 + (lane & 15)) * 32 + ko;
      bh[n] = *(const short8*)&ldsBh[b][ro];
      bl[n] = *(const short8*)&ldsBl[b][ro];
    }
#pragma unroll
    for (int m = 0; m < 4; m++)
#pragma unroll
      for (int n = 0; n < 4; n++) {
        acc[m][n] = __builtin_amdgcn_mfma_f32_16x16x32_bf16(ah[m], bh[n], acc[m][n], 0, 0, 0);
        acc[m][n] = __builtin_amdgcn_mfma_f32_16x16x32_bf16(ah[m], bl[n], acc[m][n], 0, 0, 0);
        acc[m][n] = __builtin_amdgcn_mfma_f32_16x16x32_bf16(al[m], bh[n], acc[m][n], 0, 0, 0);
      }

    __builtin_amdgcn_sched_barrier(0);
    __builtin_amdgcn_s_barrier();
  }

  // epilogue: C/D layout col=lane&15, row=(lane>>4)*4+reg; keep only
  // sim (i<5,j<5) and dot-diag (i>=5, j==i) entries, as f32.
#pragma unroll
  for (int m = 0; m < 4; m++)
#pragma unroll
    for (int n = 0; n < 4; n++)
#pragma unroll
      for (int r = 0; r < 4; r++) {
        const unsigned R = row0 + wr * 64 + m * 16 + (lane >> 4) * 4 + r;
        const unsigned Cc = col0 + wc * 64 + n * 16 + (lane & 15);
        const unsigned mq = R / 10u;
        const unsigned i = R - mq * 10u;
        const unsigned wp = Cc / 10u;
        const unsigned j = Cc - wp * 10u;
        const float val = acc[m][n][r];
        const size_t base = ((size_t)mq * 64 + wp) * 32;
        if (i < 5 && j < 5) packed[base + i * 5 + j] = val;
        else if (i >= 5 && i == j) packed[base + 25 + (i - 5)] = val;
      }
}

// Sinkhorn from packed f32 records (32 f32 per (m,w); 25 sim + 5 dot + pad).
__global__ __launch_bounds__(256) void sink2_kernel(const float* __restrict__ packed,
                                                    float* __restrict__ out)
{
  const int tid = threadIdx.x;
  const int lane = tid & 63;
  const int wv = tid >> 6;
  const int m = blockIdx.x * 4 + wv;
  const float* pb = packed + ((size_t)m * 64 + lane) * 32;

  float sm[25], dot[5];
#pragma unroll
  for (int i = 0; i < 25; i++) sm[i] = pb[i];
#pragma unroll
  for (int p = 0; p < 5; p++) dot[p] = pb[25 + p];

  out[(size_t)m * 64 + lane] = sinkhorn_core(sm, dot);
}

// ===========================================================================
// FALLBACK PATH (ws too small): R2's verified fp32 fused pipeline.
// ===========================================================================
__global__ __launch_bounds__(640) void feat_f32_kernel(const float* __restrict__ x,
                                                       float* __restrict__ outf,
                                                       int trans)
{
  __shared__ float lin[16000];
  __shared__ float wred[10][10];
  __shared__ float bc[10];
  const int n = blockIdx.x;
  const int t = threadIdx.x;
  {
    const float4* src = (const float4*)(x + (size_t)n * 16000);
    float4* dst = (float4*)lin;
#pragma unroll
    for (int i = 0; i < 6; i++) dst[t + i * 640] = src[t + i * 640];
    if (t < 160) dst[t + 3840] = src[t + 3840];
  }
  __syncthreads();
  float f[5];
  feat_compute(lin + t * 25, f, bc, wred, t);
#pragma unroll
  for (int p = 0; p < 5; p++) {
    float fv = f[p];
    float cf = (fv - bc[p]) * bc[5 + p];
    if (trans) {
      int k0 = p, k1 = 5 + p;
      outf[((size_t)t * 5 + (k0 >> 1)) * 128 + n * 2 + (k0 & 1)] = fv;
      outf[((size_t)t * 5 + (k1 >> 1)) * 128 + n * 2 + (k1 & 1)] = cf;
    } else {
      outf[((size_t)n * NC + t) * 10 + p] = fv;
      outf[((size_t)n * NC + t) * 10 + 5 + p] = cf;
    }
  }
}

__global__ __launch_bounds__(256) void sinkhorn_fused_kernel(const float* __restrict__ fq,
                                                             const float* __restrict__ fpt,
                                                             float* __restrict__ out)
{
  __shared__ float ldsP[2][CH * 5 * 128];
  __shared__ float ldsQ[2][4][CH * 10];
  const int tid = threadIdx.x;
  const int lane = tid & 63;
  const int wv = tid >> 6;
  const int m = blockIdx.x * 4 + wv;
  const float* __restrict__ qrow = fq + (size_t)m * (NC * 10);

  float dot[5] = {0.f, 0.f, 0.f, 0.f, 0.f};
  float sm[25];
#pragma unroll
  for (int i = 0; i < 25; i++) sm[i] = 0.f;

  auto stage = [&](int t, int b) {
    const float* ps = fpt + (size_t)t * (CH * 640);
#pragma unroll
    for (int i = 0; i < 5; i++) {
      int off = (wv * 5 + i) * 256 + lane * 4;
      __builtin_amdgcn_global_load_lds((glb_ptr_t)(ps + off),
                                       (lds_ptr_t)(&ldsP[b][off]), 16, 0, 0);
    }
    if (lane < 20) {
      __builtin_amdgcn_global_load_lds((glb_ptr_t)(qrow + (size_t)t * (CH * 10) + lane * 4),
                                       (lds_ptr_t)(&ldsQ[b][wv][lane * 4]), 16, 0, 0);
    }
  };

  stage(0, 0);
  for (int t = 0; t < NCH; ++t) {
    const int b = t & 1;
    if (t + 1 < NCH) {
      stage(t + 1, 1 - b);
      asm volatile("s_waitcnt vmcnt(6)" ::: "memory");
    } else {
      asm volatile("s_waitcnt vmcnt(0)" ::: "memory");
    }
    __builtin_amdgcn_sched_barrier(0);
    __builtin_amdgcn_s_barrier();

    const float* Pb = ldsP[b];
    const float* Qb = ldsQ[b][wv];
#pragma unroll
    for (int cc = 0; cc < CH; cc++) {
      float p0[10], qa[10];
#pragma unroll
      for (int j = 0; j < 5; j++) {
        float2 tp = *(const float2*)&Pb[(cc * 5 + j) * 128 + lane * 2];
        p0[2 * j] = tp.x;
        p0[2 * j + 1] = tp.y;
      }
#pragma unroll
      for (int j = 0; j < 5; j++) {
        float2 tq = *(const float2*)&Qb[cc * 10 + 2 * j];
        qa[2 * j] = tq.x;
        qa[2 * j + 1] = tq.y;
      }
#pragma unroll
      for (int p = 0; p < 5; p++) dot[p] = fmaf(qa[p], p0[p], dot[p]);
#pragma unroll
      for (int i = 0; i < 5; i++)
#pragma unroll
        for (int j = 0; j < 5; j++)
          sm[i * 5 + j] = fmaf(qa[5 + i], p0[5 + j], sm[i * 5 + j]);
    }
    __builtin_amdgcn_sched_barrier(0);
    __builtin_amdgcn_s_barrier();
  }

  out[(size_t)m * 64 + lane] = sinkhorn_core(sm, dot);
}

extern "C" void kernel_launch(void* const* d_in, const int* in_sizes, int n_in,
                              void* d_out, int out_size, void* d_ws, size_t ws_size,
                              hipStream_t stream) {
  const float* proto = (const float*)d_in[0];  // (1,64,640,5,5)
  const float* query = (const float*)d_in[1];  // (2048,640,5,5)
  float* out = (float*)d_out;                  // (2048,64) f32

  const size_t nA = (size_t)NQ * 10 * NC;   // 13,107,200 u16 per array
  const size_t nB = (size_t)NW * 10 * NC;   // 409,600 u16 per array
  const size_t needed = nA * 2 * 2 + nB * 2 * 2 + (size_t)NQ * NW * 32 * 4;

  if (ws_size >= needed) {
    u16* Ah = (u16*)d_ws;
    u16* Al = Ah + nA;
    u16* Bh = Al + nA;
    u16* Bl = Bh + nB;
    float* packed = (float*)(Bl + nB);

    feat_hl_kernel<<<NW, NC, 0, stream>>>(proto, Bh, Bl);
    feat_hl_kernel<<<NQ, NC, 0, stream>>>(query, Ah, Al);
    gemm3_kernel<<<800, 256, 0, stream>>>(Ah, Al, Bh, Bl, packed);
    sink2_kernel<<<NQ / 4, 256, 0, stream>>>(packed, out);
  } else {
    float* feat_q = (float*)d_ws;
    float* feat_pt = feat_q + (size_t)NQ * NC * 10;
    feat_f32_kernel<<<NW, NC, 0, stream>>>(proto, feat_pt, 1);
    feat_f32_kernel<<<NQ, NC, 0, stream>>>(query, feat_q, 0);
    sinkhorn_fused_kernel<<<NQ / 4, 256, 0, stream>>>(feat_q, feat_pt, out);
  }
}

// Round 5
// 115.213 us; speedup vs baseline: 2.3603x; 1.3681x over previous
//
#include <hip/hip_runtime.h>

#define NC 640
#define NQ 2048
#define NW 64

typedef unsigned short u16;
typedef unsigned int u32;
typedef __attribute__((ext_vector_type(8))) short short8;
typedef __attribute__((ext_vector_type(4))) float f32x4;
typedef __attribute__((address_space(3))) void* lds_ptr_t;
typedef const __attribute__((address_space(1))) void* glb_ptr_t;

// KC = log2(e)/EPS, EPS = 0.05
constexpr float KC = 28.853900817779268f;

static __device__ __forceinline__ float hrcp(float x) { return __builtin_amdgcn_rcpf(x); }
static __device__ __forceinline__ u16 f2bf(float f) {
  u32 u = __float_as_uint(f);
  u += 0x7FFF + ((u >> 16) & 1);
  return (u16)(u >> 16);
}
static __device__ __forceinline__ float bf2f(u16 h) {
  return __uint_as_float(((u32)h) << 16);
}

// ---------------------------------------------------------------------------
// Sinkhorn core: sim[25] + raw dot[5] (fp32) -> logit.
// ---------------------------------------------------------------------------
static __device__ __forceinline__ float sinkhorn_core(const float* sm, const float* dot) {
  float a[5];
  float suma = 0.f;
#pragma unroll
  for (int p = 0; p < 5; p++) {
    a[p] = fmaxf(dot[p], 0.f) + 0.00101f;
    suma += a[p];
  }
  float rs = 5.0f / suma;
#pragma unroll
  for (int p = 0; p < 5; p++) a[p] *= rs;

  float Km[25];
#pragma unroll
  for (int i = 0; i < 25; i++) Km[i] = __builtin_amdgcn_exp2f((sm[i] - 1.0f) * KC);

  float u[5], v[5];
#pragma unroll
  for (int p = 0; p < 5; p++) { u[p] = 1.f; v[p] = 1.f; }
  for (int it = 0; it < 100; ++it) {
#pragma unroll
    for (int i = 0; i < 5; i++) {
      float kv = Km[i * 5] * v[0];
#pragma unroll
      for (int j = 1; j < 5; j++) kv = fmaf(Km[i * 5 + j], v[j], kv);
      u[i] = a[i] * hrcp(kv);
    }
#pragma unroll
    for (int j = 0; j < 5; j++) {
      float ku = Km[j] * u[0];
#pragma unroll
      for (int i = 1; i < 5; i++) ku = fmaf(Km[i * 5 + j], u[i], ku);
      v[j] = a[j] * hrcp(ku);
    }
  }

  float acc = 0.f;
#pragma unroll
  for (int i = 0; i < 5; i++)
#pragma unroll
    for (int j = 0; j < 5; j++)
      acc += u[i] * Km[i * 5 + j] * v[j] * sm[i * 5 + j];
  return acc * 2.5f;
}

// ---------------------------------------------------------------------------
// Per-thread patch means + block stats. bc = {mu[5], nrm[5]} (nrm guarded).
// ---------------------------------------------------------------------------
static __device__ __forceinline__ void feat_compute(const float* v, float* f,
                                                    float* bc, float (*wred)[10],
                                                    int t) {
  {
    float lt = 0.f, rt = 0.f, mid = 0.f, lb = 0.f, rb = 0.f;
#pragma unroll
    for (int i = 0; i < 3; i++)
#pragma unroll
      for (int j = 0; j < 3; j++) {
        lt += v[i * 5 + j];
        rt += v[(i + 2) * 5 + j];
        lb += v[i * 5 + (j + 2)];
        rb += v[(i + 2) * 5 + (j + 2)];
      }
#pragma unroll
    for (int i = 1; i < 5; i++)
#pragma unroll
      for (int j = 1; j < 5; j++) mid += v[i * 5 + j];
    f[0] = lt * (1.f / 9.f);
    f[1] = rt * (1.f / 9.f);
    f[2] = mid * (1.f / 16.f);
    f[3] = lb * (1.f / 9.f);
    f[4] = rb * (1.f / 9.f);
  }
  float s[10];
#pragma unroll
  for (int p = 0; p < 5; p++) { s[p] = f[p]; s[5 + p] = f[p] * f[p]; }
#pragma unroll
  for (int off = 32; off > 0; off >>= 1)
#pragma unroll
    for (int k = 0; k < 10; k++) s[k] += __shfl_xor(s[k], off);
  const int lane = t & 63;
  const int wv = t >> 6;
  if (lane == 0) {
#pragma unroll
    for (int k = 0; k < 10; k++) wred[wv][k] = s[k];
  }
  __syncthreads();
  if (t < 5) {
    float s1 = 0.f, s2 = 0.f;
#pragma unroll
    for (int w = 0; w < 10; w++) { s1 += wred[w][t]; s2 += wred[w][5 + t]; }
    float mu = s1 * (1.0f / NC);
    float n2 = fmaxf(s2 - (float)NC * mu * mu, 0.0f);
    float nrm = fmaxf(sqrtf(n2), 1e-8f);
    bc[t] = mu;
    bc[5 + t] = nrm;
  }
  __syncthreads();
}

// ---------------------------------------------------------------------------
// Feature kernel: 5 centered-normalized rows per n as split-bf16 [n*5+p][640],
// plus stats {mu, nrm} per (n,p).
// proto_layout=1: stats[p][64] / stats[5+p][64];  =0: stats[n][10].
// ---------------------------------------------------------------------------
__global__ __launch_bounds__(640) void feat_hl_kernel(const float* __restrict__ x,
                                                      u16* __restrict__ outh,
                                                      u16* __restrict__ outl,
                                                      float* __restrict__ stats,
                                                      int proto_layout)
{
  __shared__ float lin[16000];
  __shared__ float wred[10][10];
  __shared__ float bc[10];
  const int n = blockIdx.x;
  const int t = threadIdx.x;

  {
    const float4* src = (const float4*)(x + (size_t)n * 16000);
    float4* dst = (float4*)lin;
#pragma unroll
    for (int i = 0; i < 6; i++) dst[t + i * 640] = src[t + i * 640];
    if (t < 160) dst[t + 3840] = src[t + 3840];
  }
  __syncthreads();

  float f[5];
  feat_compute(lin + t * 25, f, bc, wred, t);

  if (t < 5) {
    if (proto_layout) {
      stats[t * NW + n] = bc[t];
      stats[(5 + t) * NW + n] = bc[5 + t];
    } else {
      stats[(size_t)n * 10 + t] = bc[t];
      stats[(size_t)n * 10 + 5 + t] = bc[5 + t];
    }
  }

  float* lout = lin;  // reuse: 5 rows x 640
#pragma unroll
  for (int p = 0; p < 5; p++)
    lout[p * 640 + t] = (f[p] - bc[p]) * (1.0f / bc[5 + p]);
  __syncthreads();

  // write 1600 u32 (hi) + 1600 u32 (lo), coalesced
  u32* outhu = (u32*)outh;
  u32* outlu = (u32*)outl;
#pragma unroll
  for (int i = 0; i < 3; i++) {
    int j = t + i * 640;            // 0..1919, need <1600
    if (i == 2 && t >= 320) break;
    int k = j / 320;
    int cp = j - k * 320;
    float f0 = lout[k * 640 + cp * 2];
    float f1 = lout[k * 640 + cp * 2 + 1];
    u16 h0 = f2bf(f0), h1 = f2bf(f1);
    float l0 = f0 - bf2f(h0);
    float l1 = f1 - bf2f(h1);
    size_t o = ((size_t)n * 5 + k) * 320 + cp;
    outhu[o] = (u32)h0 | ((u32)h1 << 16);
    outlu[o] = (u32)f2bf(l0) | ((u32)f2bf(l1) << 16);
  }
}

// ---------------------------------------------------------------------------
// sim GEMM: C[10240][320] = A[10240][640] * Bt[320][640]^T, split-bf16 3-pass.
// Tile 128x64, BK=32, 4 waves (2x2), dbuf LDS 48KB, global_load_lds w16 with
// XOR-swizzled source (phys = logical ^ (((row>>1)&3)<<4)), swizzled ds_read
// -> 2-way (free) bank access. Counted vmcnt(6). Epilogue -> packed f32.
// ---------------------------------------------------------------------------
__global__ __launch_bounds__(256) void gemm_sim_kernel(const u16* __restrict__ Ah,
                                                       const u16* __restrict__ Al,
                                                       const u16* __restrict__ Bh,
                                                       const u16* __restrict__ Bl,
                                                       float* __restrict__ packed)
{
  __shared__ u16 ldsAh[2][128 * 32];
  __shared__ u16 ldsAl[2][128 * 32];
  __shared__ u16 ldsBh[2][64 * 32];
  __shared__ u16 ldsBl[2][64 * 32];
  const int bid = blockIdx.x;
  const int wg = (bid & 7) * 50 + (bid >> 3);  // bijective, 400 = 8*50
  const int bm = wg / 5;
  const int bn = wg % 5;
  const int row0 = bm * 128;
  const int col0 = bn * 64;
  const int tid = threadIdx.x;
  const int lane = tid & 63;
  const int w = tid >> 6;
  const int wr = w >> 1;
  const int wc = w & 1;

  f32x4 acc[4][2];
#pragma unroll
  for (int m = 0; m < 4; m++)
#pragma unroll
    for (int n = 0; n < 2; n++) acc[m][n] = (f32x4){0.f, 0.f, 0.f, 0.f};

  auto stage = [&](int kt, int b) {
    const int k0 = kt * 32;
#pragma unroll
    for (int i = 0; i < 2; i++) {
      const int s = tid + i * 256;
      const int r = s >> 2;
      const int chl = (s & 3) ^ ((r >> 1) & 3);  // pre-swizzled source slot
      const size_t go = (size_t)(row0 + r) * 640 + k0 + chl * 8;
      __builtin_amdgcn_global_load_lds((glb_ptr_t)(Ah + go),
                                       (lds_ptr_t)(&ldsAh[b][s * 8]), 16, 0, 0);
      __builtin_amdgcn_global_load_lds((glb_ptr_t)(Al + go),
                                       (lds_ptr_t)(&ldsAl[b][s * 8]), 16, 0, 0);
    }
    {
      const int r = tid >> 2;
      const int chl = (tid & 3) ^ ((r >> 1) & 3);
      const size_t go = (size_t)(col0 + r) * 640 + k0 + chl * 8;
      __builtin_amdgcn_global_load_lds((glb_ptr_t)(Bh + go),
                                       (lds_ptr_t)(&ldsBh[b][tid * 8]), 16, 0, 0);
      __builtin_amdgcn_global_load_lds((glb_ptr_t)(Bl + go),
                                       (lds_ptr_t)(&ldsBl[b][tid * 8]), 16, 0, 0);
    }
  };

  stage(0, 0);
  for (int kt = 0; kt < 20; ++kt) {
    const int b = kt & 1;
    if (kt < 19) {
      stage(kt + 1, b ^ 1);
      asm volatile("s_waitcnt vmcnt(6)" ::: "memory");
    } else {
      asm volatile("s_waitcnt vmcnt(0)" ::: "memory");
    }
    __builtin_amdgcn_sched_barrier(0);
    __builtin_amdgcn_s_barrier();

    const int rq = lane & 15;
    const int kq = lane >> 4;
    short8 ah[4], al[4], bh[2], bl[2];
#pragma unroll
    for (int m = 0; m < 4; m++) {
      const int row = wr * 64 + m * 16 + rq;
      const int off = row * 32 + ((kq ^ ((row >> 1) & 3)) * 8);
      ah[m] = *(const short8*)&ldsAh[b][off];
      al[m] = *(const short8*)&ldsAl[b][off];
    }
#pragma unroll
    for (int n = 0; n < 2; n++) {
      const int row = wc * 32 + n * 16 + rq;
      const int off = row * 32 + ((kq ^ ((row >> 1) & 3)) * 8);
      bh[n] = *(const short8*)&ldsBh[b][off];
      bl[n] = *(const short8*)&ldsBl[b][off];
    }
#pragma unroll
    for (int m = 0; m < 4; m++)
#pragma unroll
      for (int n = 0; n < 2; n++) {
        acc[m][n] = __builtin_amdgcn_mfma_f32_16x16x32_bf16(ah[m], bh[n], acc[m][n], 0, 0, 0);
        acc[m][n] = __builtin_amdgcn_mfma_f32_16x16x32_bf16(ah[m], bl[n], acc[m][n], 0, 0, 0);
        acc[m][n] = __builtin_amdgcn_mfma_f32_16x16x32_bf16(al[m], bh[n], acc[m][n], 0, 0, 0);
      }

    __builtin_amdgcn_sched_barrier(0);
    __builtin_amdgcn_s_barrier();
  }

  // epilogue: C/D layout col=lane&15, row=(lane>>4)*4+reg (m89)
#pragma unroll
  for (int m = 0; m < 4; m++)
#pragma unroll
    for (int n = 0; n < 2; n++)
#pragma unroll
      for (int r = 0; r < 4; r++) {
        const unsigned R = row0 + wr * 64 + m * 16 + (lane >> 4) * 4 + r;
        const unsigned Cc = col0 + wc * 32 + n * 16 + (lane & 15);
        const unsigned mq = R / 5u;
        const unsigned i = R - mq * 5u;
        const unsigned wp = Cc / 5u;
        const unsigned j = Cc - wp * 5u;
        packed[((size_t)mq * 64 + wp) * 32 + i * 5 + j] = acc[m][n][r];
      }
}

// ---------------------------------------------------------------------------
// Sinkhorn: thread <-> (m,w). dot reconstructed from sim diagonal + stats:
//   rawdot[p] = sim[p,p]*nrm_q[p]*nrm_p[p] + 640*mu_q[p]*mu_p[p]
// ---------------------------------------------------------------------------
__global__ __launch_bounds__(256) void sink3_kernel(const float* __restrict__ packed,
                                                    const float* __restrict__ statsQ,
                                                    const float* __restrict__ statsP,
                                                    float* __restrict__ out)
{
  const int tid = threadIdx.x;
  const int lane = tid & 63;
  const int wv = tid >> 6;
  const int m = blockIdx.x * 4 + wv;
  const float* pb = packed + ((size_t)m * 64 + lane) * 32;

  float sm[25];
  {
    const f32x4* pv = (const f32x4*)pb;
#pragma unroll
    for (int q = 0; q < 6; q++) {
      f32x4 t = pv[q];
#pragma unroll
      for (int e = 0; e < 4; e++) sm[q * 4 + e] = t[e];
    }
    sm[24] = pb[24];
  }

  float dot[5];
#pragma unroll
  for (int p = 0; p < 5; p++) {
    float muq = statsQ[(size_t)m * 10 + p];
    float nq = statsQ[(size_t)m * 10 + 5 + p];
    float mup = statsP[p * NW + lane];
    float np = statsP[(5 + p) * NW + lane];
    dot[p] = sm[p * 5 + p] * (nq * np) + 640.0f * muq * mup;
  }

  out[(size_t)m * 64 + lane] = sinkhorn_core(sm, dot);
}

extern "C" void kernel_launch(void* const* d_in, const int* in_sizes, int n_in,
                              void* d_out, int out_size, void* d_ws, size_t ws_size,
                              hipStream_t stream) {
  const float* proto = (const float*)d_in[0];  // (1,64,640,5,5)
  const float* query = (const float*)d_in[1];  // (2048,640,5,5)
  float* out = (float*)d_out;                  // (2048,64) f32

  // ws: Ah|Al (10240x640 u16 each) | Bh|Bl (320x640 u16 each)
  //     | statsQ (2048x10 f32) | statsP (10x64 f32) | packed (2048*64*32 f32)
  const size_t nA = (size_t)NQ * 5 * NC;   // 6,553,600
  const size_t nB = (size_t)NW * 5 * NC;   // 204,800
  u16* Ah = (u16*)d_ws;
  u16* Al = Ah + nA;
  u16* Bh = Al + nA;
  u16* Bl = Bh + nB;
  float* statsQ = (float*)(Bl + nB);
  float* statsP = statsQ + (size_t)NQ * 10;
  float* packed = statsP + 10 * NW;

  feat_hl_kernel<<<NW, NC, 0, stream>>>(proto, Bh, Bl, statsP, 1);
  feat_hl_kernel<<<NQ, NC, 0, stream>>>(query, Ah, Al, statsQ, 0);
  gemm_sim_kernel<<<400, 256, 0, stream>>>(Ah, Al, Bh, Bl, packed);
  sink3_kernel<<<NQ / 4, 256, 0, stream>>>(packed, statsQ, statsP, out);
}

// Round 6
// 110.542 us; speedup vs baseline: 2.4601x; 1.0423x over previous
//
#include <hip/hip_runtime.h>

#define NC 640
#define NQ 2048
#define NW 64

typedef unsigned short u16;
typedef unsigned int u32;
typedef __attribute__((ext_vector_type(8))) short short8;
typedef __attribute__((ext_vector_type(4))) float f32x4;
typedef __attribute__((ext_vector_type(2))) float f32x2;
typedef __attribute__((address_space(3))) void* lds_ptr_t;
typedef const __attribute__((address_space(1))) void* glb_ptr_t;

// KC = log2(e)/EPS, EPS = 0.05
constexpr float KC = 28.853900817779268f;

static __device__ __forceinline__ float hrcp(float x) { return __builtin_amdgcn_rcpf(x); }
static __device__ __forceinline__ u16 f2bf(float f) {
  u32 u = __float_as_uint(f);
  u += 0x7FFF + ((u >> 16) & 1);
  return (u16)(u >> 16);
}
static __device__ __forceinline__ float bf2f(u16 h) {
  return __uint_as_float(((u32)h) << 16);
}

// ---------------------------------------------------------------------------
// Sinkhorn core with f32x2-packed FMA chains (v_pk_fma_f32).
// ---------------------------------------------------------------------------
static __device__ __forceinline__ float sinkhorn_core(const float* sm, const float* dot) {
  float a[5];
  float suma = 0.f;
#pragma unroll
  for (int p = 0; p < 5; p++) {
    a[p] = fmaxf(dot[p], 0.f) + 0.00101f;
    suma += a[p];
  }
  float rs = 5.0f / suma;
#pragma unroll
  for (int p = 0; p < 5; p++) a[p] *= rs;

  float Km[25];
#pragma unroll
  for (int i = 0; i < 25; i++) Km[i] = __builtin_amdgcn_exp2f((sm[i] - 1.0f) * KC);

  // row-pair packs (for u-phase): KP01[j] = {K0j, K1j}, KP23[j] = {K2j, K3j}
  f32x2 KP01[5], KP23[5];
  // col-pair packs (for v-phase): KQ01[i] = {Ki0, Ki1}, KQ23[i] = {Ki2, Ki3}
  f32x2 KQ01[5], KQ23[5];
#pragma unroll
  for (int j = 0; j < 5; j++) {
    KP01[j] = (f32x2){Km[0 * 5 + j], Km[1 * 5 + j]};
    KP23[j] = (f32x2){Km[2 * 5 + j], Km[3 * 5 + j]};
  }
#pragma unroll
  for (int i = 0; i < 5; i++) {
    KQ01[i] = (f32x2){Km[i * 5 + 0], Km[i * 5 + 1]};
    KQ23[i] = (f32x2){Km[i * 5 + 2], Km[i * 5 + 3]};
  }

  float u[5], v[5];
#pragma unroll
  for (int p = 0; p < 5; p++) { u[p] = 1.f; v[p] = 1.f; }

  for (int it = 0; it < 100; ++it) {
    // u-phase: kv_i = sum_j K_ij v_j
    f32x2 kv01 = (f32x2){0.f, 0.f}, kv23 = (f32x2){0.f, 0.f};
    float kv4 = 0.f;
#pragma unroll
    for (int j = 0; j < 5; j++) {
      f32x2 vb = (f32x2){v[j], v[j]};
      kv01 = __builtin_elementwise_fma(KP01[j], vb, kv01);
      kv23 = __builtin_elementwise_fma(KP23[j], vb, kv23);
      kv4 = fmaf(Km[20 + j], v[j], kv4);
    }
    u[0] = a[0] * hrcp(kv01.x);
    u[1] = a[1] * hrcp(kv01.y);
    u[2] = a[2] * hrcp(kv23.x);
    u[3] = a[3] * hrcp(kv23.y);
    u[4] = a[4] * hrcp(kv4);
    // v-phase: ku_j = sum_i K_ij u_i
    f32x2 ku01 = (f32x2){0.f, 0.f}, ku23 = (f32x2){0.f, 0.f};
    float ku4 = 0.f;
#pragma unroll
    for (int i = 0; i < 5; i++) {
      f32x2 ub = (f32x2){u[i], u[i]};
      ku01 = __builtin_elementwise_fma(KQ01[i], ub, ku01);
      ku23 = __builtin_elementwise_fma(KQ23[i], ub, ku23);
      ku4 = fmaf(Km[i * 5 + 4], u[i], ku4);
    }
    v[0] = a[0] * hrcp(ku01.x);
    v[1] = a[1] * hrcp(ku01.y);
    v[2] = a[2] * hrcp(ku23.x);
    v[3] = a[3] * hrcp(ku23.y);
    v[4] = a[4] * hrcp(ku4);
  }

  float acc = 0.f;
#pragma unroll
  for (int i = 0; i < 5; i++)
#pragma unroll
    for (int j = 0; j < 5; j++)
      acc += u[i] * Km[i * 5 + j] * v[j] * sm[i * 5 + j];
  return acc * 2.5f;
}

// ---------------------------------------------------------------------------
// Fused feature kernel, LDS-free: one WAVE per sample n; lane owns channels
// 10*lane .. 10*lane+9 (contiguous 1000B -> L1-reused lines). Register
// partials + one 6-level shfl_xor reduce. Blocks 0..511: query; 512..527: proto.
// Outputs: split-bf16 rows [n*5+p][640] (hi/lo) + per-(n,p) {mu, nrm} stats.
// ---------------------------------------------------------------------------
__global__ __launch_bounds__(256) void feat_kernel(const float* __restrict__ q,
                                                   const float* __restrict__ pr,
                                                   u16* __restrict__ Ah,
                                                   u16* __restrict__ Al,
                                                   u16* __restrict__ Bh,
                                                   u16* __restrict__ Bl,
                                                   float* __restrict__ statsQ,
                                                   float* __restrict__ statsP)
{
  const int bid = blockIdx.x;
  const int lane = threadIdx.x & 63;
  const int wv = threadIdx.x >> 6;
  const bool isQ = (bid < 512);
  const int n = (isQ ? bid : bid - 512) * 4 + wv;
  const float* __restrict__ x = (isQ ? q : pr) + (size_t)n * 16000;
  const float* base = x + lane * 250;   // 10 channels x 25 floats

  float f[10][5];
  float s1[5] = {0.f, 0.f, 0.f, 0.f, 0.f};
  float s2[5] = {0.f, 0.f, 0.f, 0.f, 0.f};

#pragma unroll
  for (int j = 0; j < 10; j++) {
    const float* v = base + j * 25;
    float w[25];
#pragma unroll
    for (int i = 0; i < 25; i++) w[i] = v[i];
    float lt = 0.f, rt = 0.f, mid = 0.f, lb = 0.f, rb = 0.f;
#pragma unroll
    for (int a = 0; a < 3; a++)
#pragma unroll
      for (int b = 0; b < 3; b++) {
        lt += w[a * 5 + b];
        rt += w[(a + 2) * 5 + b];
        lb += w[a * 5 + (b + 2)];
        rb += w[(a + 2) * 5 + (b + 2)];
      }
#pragma unroll
    for (int a = 1; a < 5; a++)
#pragma unroll
      for (int b = 1; b < 5; b++) mid += w[a * 5 + b];
    f[j][0] = lt * (1.f / 9.f);
    f[j][1] = rt * (1.f / 9.f);
    f[j][2] = mid * (1.f / 16.f);
    f[j][3] = lb * (1.f / 9.f);
    f[j][4] = rb * (1.f / 9.f);
#pragma unroll
    for (int p = 0; p < 5; p++) {
      s1[p] += f[j][p];
      s2[p] = fmaf(f[j][p], f[j][p], s2[p]);
    }
  }

  // wave reduction (64 lanes)
#pragma unroll
  for (int off = 32; off > 0; off >>= 1)
#pragma unroll
    for (int p = 0; p < 5; p++) {
      s1[p] += __shfl_xor(s1[p], off);
      s2[p] += __shfl_xor(s2[p], off);
    }

  float mu[5], rn[5], nrm[5];
#pragma unroll
  for (int p = 0; p < 5; p++) {
    mu[p] = s1[p] * (1.0f / NC);
    float n2 = fmaxf(s2[p] - (float)NC * mu[p] * mu[p], 0.0f);
    nrm[p] = fmaxf(sqrtf(n2), 1e-8f);
    rn[p] = 1.0f / nrm[p];
  }

  if (lane == 0) {
    if (isQ) {
#pragma unroll
      for (int p = 0; p < 5; p++) {
        statsQ[(size_t)n * 10 + p] = mu[p];
        statsQ[(size_t)n * 10 + 5 + p] = nrm[p];
      }
    } else {
#pragma unroll
      for (int p = 0; p < 5; p++) {
        statsP[p * NW + n] = mu[p];
        statsP[(5 + p) * NW + n] = nrm[p];
      }
    }
  }

  // centered-normalized split-bf16 writes: pack channel pairs (10L+2s, 10L+2s+1)
  u32* outh = (u32*)(isQ ? Ah : Bh);
  u32* outl = (u32*)(isQ ? Al : Bl);
#pragma unroll
  for (int p = 0; p < 5; p++) {
    const size_t rowb = ((size_t)n * 5 + p) * 320 + 5 * lane;
#pragma unroll
    for (int s = 0; s < 5; s++) {
      float g0 = (f[2 * s][p] - mu[p]) * rn[p];
      float g1 = (f[2 * s + 1][p] - mu[p]) * rn[p];
      u16 h0 = f2bf(g0), h1 = f2bf(g1);
      float l0 = g0 - bf2f(h0);
      float l1 = g1 - bf2f(h1);
      outh[rowb + s] = (u32)h0 | ((u32)h1 << 16);
      outl[rowb + s] = (u32)f2bf(l0) | ((u32)f2bf(l1) << 16);
    }
  }
}

// ---------------------------------------------------------------------------
// sim GEMM: C[10240][320] = A[10240][640] * Bt[320][640]^T, split-bf16 3-pass.
// Tile 128x64, BK=32, 4 waves (2x2), dbuf LDS, XOR-swizzled both sides,
// counted vmcnt(6). Epilogue -> packed f32 (unchanged from R5, verified).
// ---------------------------------------------------------------------------
__global__ __launch_bounds__(256) void gemm_sim_kernel(const u16* __restrict__ Ah,
                                                       const u16* __restrict__ Al,
                                                       const u16* __restrict__ Bh,
                                                       const u16* __restrict__ Bl,
                                                       float* __restrict__ packed)
{
  __shared__ u16 ldsAh[2][128 * 32];
  __shared__ u16 ldsAl[2][128 * 32];
  __shared__ u16 ldsBh[2][64 * 32];
  __shared__ u16 ldsBl[2][64 * 32];
  const int bid = blockIdx.x;
  const int wg = (bid & 7) * 50 + (bid >> 3);  // bijective, 400 = 8*50
  const int bm = wg / 5;
  const int bn = wg % 5;
  const int row0 = bm * 128;
  const int col0 = bn * 64;
  const int tid = threadIdx.x;
  const int lane = tid & 63;
  const int w = tid >> 6;
  const int wr = w >> 1;
  const int wc = w & 1;

  f32x4 acc[4][2];
#pragma unroll
  for (int m = 0; m < 4; m++)
#pragma unroll
    for (int n = 0; n < 2; n++) acc[m][n] = (f32x4){0.f, 0.f, 0.f, 0.f};

  auto stage = [&](int kt, int b) {
    const int k0 = kt * 32;
#pragma unroll
    for (int i = 0; i < 2; i++) {
      const int s = tid + i * 256;
      const int r = s >> 2;
      const int chl = (s & 3) ^ ((r >> 1) & 3);  // pre-swizzled source slot
      const size_t go = (size_t)(row0 + r) * 640 + k0 + chl * 8;
      __builtin_amdgcn_global_load_lds((glb_ptr_t)(Ah + go),
                                       (lds_ptr_t)(&ldsAh[b][s * 8]), 16, 0, 0);
      __builtin_amdgcn_global_load_lds((glb_ptr_t)(Al + go),
                                       (lds_ptr_t)(&ldsAl[b][s * 8]), 16, 0, 0);
    }
    {
      const int r = tid >> 2;
      const int chl = (tid & 3) ^ ((r >> 1) & 3);
      const size_t go = (size_t)(col0 + r) * 640 + k0 + chl * 8;
      __builtin_amdgcn_global_load_lds((glb_ptr_t)(Bh + go),
                                       (lds_ptr_t)(&ldsBh[b][tid * 8]), 16, 0, 0);
      __builtin_amdgcn_global_load_lds((glb_ptr_t)(Bl + go),
                                       (lds_ptr_t)(&ldsBl[b][tid * 8]), 16, 0, 0);
    }
  };

  stage(0, 0);
  for (int kt = 0; kt < 20; ++kt) {
    const int b = kt & 1;
    if (kt < 19) {
      stage(kt + 1, b ^ 1);
      asm volatile("s_waitcnt vmcnt(6)" ::: "memory");
    } else {
      asm volatile("s_waitcnt vmcnt(0)" ::: "memory");
    }
    __builtin_amdgcn_sched_barrier(0);
    __builtin_amdgcn_s_barrier();

    const int rq = lane & 15;
    const int kq = lane >> 4;
    short8 ah[4], al[4], bh[2], bl[2];
#pragma unroll
    for (int m = 0; m < 4; m++) {
      const int row = wr * 64 + m * 16 + rq;
      const int off = row * 32 + ((kq ^ ((row >> 1) & 3)) * 8);
      ah[m] = *(const short8*)&ldsAh[b][off];
      al[m] = *(const short8*)&ldsAl[b][off];
    }
#pragma unroll
    for (int n = 0; n < 2; n++) {
      const int row = wc * 32 + n * 16 + rq;
      const int off = row * 32 + ((kq ^ ((row >> 1) & 3)) * 8);
      bh[n] = *(const short8*)&ldsBh[b][off];
      bl[n] = *(const short8*)&ldsBl[b][off];
    }
#pragma unroll
    for (int m = 0; m < 4; m++)
#pragma unroll
      for (int n = 0; n < 2; n++) {
        acc[m][n] = __builtin_amdgcn_mfma_f32_16x16x32_bf16(ah[m], bh[n], acc[m][n], 0, 0, 0);
        acc[m][n] = __builtin_amdgcn_mfma_f32_16x16x32_bf16(ah[m], bl[n], acc[m][n], 0, 0, 0);
        acc[m][n] = __builtin_amdgcn_mfma_f32_16x16x32_bf16(al[m], bh[n], acc[m][n], 0, 0, 0);
      }

    __builtin_amdgcn_sched_barrier(0);
    __builtin_amdgcn_s_barrier();
  }

  // epilogue: C/D layout col=lane&15, row=(lane>>4)*4+reg
#pragma unroll
  for (int m = 0; m < 4; m++)
#pragma unroll
    for (int n = 0; n < 2; n++)
#pragma unroll
      for (int r = 0; r < 4; r++) {
        const unsigned R = row0 + wr * 64 + m * 16 + (lane >> 4) * 4 + r;
        const unsigned Cc = col0 + wc * 32 + n * 16 + (lane & 15);
        const unsigned mq = R / 5u;
        const unsigned i = R - mq * 5u;
        const unsigned wp = Cc / 5u;
        const unsigned j = Cc - wp * 5u;
        packed[((size_t)mq * 64 + wp) * 32 + i * 5 + j] = acc[m][n][r];
      }
}

// ---------------------------------------------------------------------------
// Sinkhorn: thread <-> (m,w). dot reconstructed from sim diagonal + stats.
// ---------------------------------------------------------------------------
__global__ __launch_bounds__(256) void sink3_kernel(const float* __restrict__ packed,
                                                    const float* __restrict__ statsQ,
                                                    const float* __restrict__ statsP,
                                                    float* __restrict__ out)
{
  const int tid = threadIdx.x;
  const int lane = tid & 63;
  const int wv = tid >> 6;
  const int m = blockIdx.x * 4 + wv;
  const float* pb = packed + ((size_t)m * 64 + lane) * 32;

  float sm[25];
  {
    const f32x4* pv = (const f32x4*)pb;
#pragma unroll
    for (int q = 0; q < 6; q++) {
      f32x4 t = pv[q];
#pragma unroll
      for (int e = 0; e < 4; e++) sm[q * 4 + e] = t[e];
    }
    sm[24] = pb[24];
  }

  float dot[5];
#pragma unroll
  for (int p = 0; p < 5; p++) {
    float muq = statsQ[(size_t)m * 10 + p];
    float nq = statsQ[(size_t)m * 10 + 5 + p];
    float mup = statsP[p * NW + lane];
    float np = statsP[(5 + p) * NW + lane];
    dot[p] = sm[p * 5 + p] * (nq * np) + 640.0f * muq * mup;
  }

  out[(size_t)m * 64 + lane] = sinkhorn_core(sm, dot);
}

extern "C" void kernel_launch(void* const* d_in, const int* in_sizes, int n_in,
                              void* d_out, int out_size, void* d_ws, size_t ws_size,
                              hipStream_t stream) {
  const float* proto = (const float*)d_in[0];  // (1,64,640,5,5)
  const float* query = (const float*)d_in[1];  // (2048,640,5,5)
  float* out = (float*)d_out;                  // (2048,64) f32

  const size_t nA = (size_t)NQ * 5 * NC;   // 6,553,600 u16
  const size_t nB = (size_t)NW * 5 * NC;   // 204,800 u16
  u16* Ah = (u16*)d_ws;
  u16* Al = Ah + nA;
  u16* Bh = Al + nA;
  u16* Bl = Bh + nB;
  float* statsQ = (float*)(Bl + nB);
  float* statsP = statsQ + (size_t)NQ * 10;
  float* packed = statsP + 10 * NW;

  feat_kernel<<<528, 256, 0, stream>>>(query, proto, Ah, Al, Bh, Bl, statsQ, statsP);
  gemm_sim_kernel<<<400, 256, 0, stream>>>(Ah, Al, Bh, Bl, packed);
  sink3_kernel<<<NQ / 4, 256, 0, stream>>>(packed, statsQ, statsP, out);
}

// Round 7
// 84.762 us; speedup vs baseline: 3.2083x; 1.3041x over previous
//
#include <hip/hip_runtime.h>

#define NC 640
#define NQ 2048
#define NW 64

typedef unsigned short u16;
typedef unsigned int u32;
typedef __attribute__((ext_vector_type(8))) short short8;
typedef __attribute__((ext_vector_type(4))) float f32x4;
typedef __attribute__((ext_vector_type(2))) float f32x2;
typedef __attribute__((address_space(3))) void* lds_ptr_t;
typedef const __attribute__((address_space(1))) void* glb_ptr_t;

// KC = log2(e)/EPS, EPS = 0.05
constexpr float KC = 28.853900817779268f;

static __device__ __forceinline__ float hrcp(float x) { return __builtin_amdgcn_rcpf(x); }
static __device__ __forceinline__ u16 f2bf(float f) {
  u32 u = __float_as_uint(f);
  u += 0x7FFF + ((u >> 16) & 1);
  return (u16)(u >> 16);
}
static __device__ __forceinline__ float bf2f(u16 h) {
  return __uint_as_float(((u32)h) << 16);
}

// ---------------------------------------------------------------------------
// Sinkhorn core with f32x2-packed FMA chains (v_pk_fma_f32).
// ---------------------------------------------------------------------------
static __device__ __forceinline__ float sinkhorn_core(const float* sm, const float* dot) {
  float a[5];
  float suma = 0.f;
#pragma unroll
  for (int p = 0; p < 5; p++) {
    a[p] = fmaxf(dot[p], 0.f) + 0.00101f;
    suma += a[p];
  }
  float rs = 5.0f / suma;
#pragma unroll
  for (int p = 0; p < 5; p++) a[p] *= rs;

  float Km[25];
#pragma unroll
  for (int i = 0; i < 25; i++) Km[i] = __builtin_amdgcn_exp2f((sm[i] - 1.0f) * KC);

  f32x2 KP01[5], KP23[5], KQ01[5], KQ23[5];
#pragma unroll
  for (int j = 0; j < 5; j++) {
    KP01[j] = (f32x2){Km[0 * 5 + j], Km[1 * 5 + j]};
    KP23[j] = (f32x2){Km[2 * 5 + j], Km[3 * 5 + j]};
  }
#pragma unroll
  for (int i = 0; i < 5; i++) {
    KQ01[i] = (f32x2){Km[i * 5 + 0], Km[i * 5 + 1]};
    KQ23[i] = (f32x2){Km[i * 5 + 2], Km[i * 5 + 3]};
  }

  float u[5], v[5];
#pragma unroll
  for (int p = 0; p < 5; p++) { u[p] = 1.f; v[p] = 1.f; }

  for (int it = 0; it < 100; ++it) {
    f32x2 kv01 = (f32x2){0.f, 0.f}, kv23 = (f32x2){0.f, 0.f};
    float kv4 = 0.f;
#pragma unroll
    for (int j = 0; j < 5; j++) {
      f32x2 vb = (f32x2){v[j], v[j]};
      kv01 = __builtin_elementwise_fma(KP01[j], vb, kv01);
      kv23 = __builtin_elementwise_fma(KP23[j], vb, kv23);
      kv4 = fmaf(Km[20 + j], v[j], kv4);
    }
    u[0] = a[0] * hrcp(kv01.x);
    u[1] = a[1] * hrcp(kv01.y);
    u[2] = a[2] * hrcp(kv23.x);
    u[3] = a[3] * hrcp(kv23.y);
    u[4] = a[4] * hrcp(kv4);
    f32x2 ku01 = (f32x2){0.f, 0.f}, ku23 = (f32x2){0.f, 0.f};
    float ku4 = 0.f;
#pragma unroll
    for (int i = 0; i < 5; i++) {
      f32x2 ub = (f32x2){u[i], u[i]};
      ku01 = __builtin_elementwise_fma(KQ01[i], ub, ku01);
      ku23 = __builtin_elementwise_fma(KQ23[i], ub, ku23);
      ku4 = fmaf(Km[i * 5 + 4], u[i], ku4);
    }
    v[0] = a[0] * hrcp(ku01.x);
    v[1] = a[1] * hrcp(ku01.y);
    v[2] = a[2] * hrcp(ku23.x);
    v[3] = a[3] * hrcp(ku23.y);
    v[4] = a[4] * hrcp(ku4);
  }

  float acc = 0.f;
#pragma unroll
  for (int i = 0; i < 5; i++)
#pragma unroll
    for (int j = 0; j < 5; j++)
      acc += u[i] * Km[i * 5 + j] * v[j] * sm[i * 5 + j];
  return acc * 2.5f;
}

// ---------------------------------------------------------------------------
// Feature kernel v3: wave = half-sample (320 channels, 5 chunks of 64).
// Chunk = linear 6.4KB DMA (global_load_lds, 6x16B + 1x4B per lane,
// coalesced), per-wave double-buffered, vmcnt(7). Lane reads its own channel
// (l*25+j: conflict-free). One __syncthreads only for the 2-wave pair reduce.
// Block = 2 samples (4 waves). Blocks [0,1024): query; [1024,1056): proto.
// ---------------------------------------------------------------------------
__global__ __launch_bounds__(256) void feat_kernel(const float* __restrict__ q,
                                                   const float* __restrict__ pr,
                                                   u16* __restrict__ Ah,
                                                   u16* __restrict__ Al,
                                                   u16* __restrict__ Bh,
                                                   u16* __restrict__ Bl,
                                                   float* __restrict__ statsQ,
                                                   float* __restrict__ statsP)
{
  __shared__ float ldsW[4][2][1600];   // 51.2 KB: per-wave double buffer
  __shared__ float sred[4][10];
  const int lane = threadIdx.x & 63;
  const int wv = threadIdx.x >> 6;
  const int sid = blockIdx.x * 2 + (wv >> 1);   // sample id 0..2111
  const int h = wv & 1;                          // half: channels [320h, 320h+320)
  const bool isQ = (sid < NQ);
  const int n = isQ ? sid : sid - NQ;
  const float* __restrict__ x = (isQ ? q : pr) + (size_t)n * 16000;

  // stage chunk k (64 channels = 1600 floats) into buffer b, linear copy
  auto stage = [&](int k, int b) {
    asm volatile("s_waitcnt lgkmcnt(0)" ::: "memory");  // prior reads of b done
    const float* src = x + (size_t)(h * 320 + k * 64) * 25;
#pragma unroll
    for (int i = 0; i < 6; i++) {
      __builtin_amdgcn_global_load_lds((glb_ptr_t)(src + i * 256 + lane * 4),
                                       (lds_ptr_t)(&ldsW[wv][b][i * 256 + lane * 4]),
                                       16, 0, 0);
    }
    __builtin_amdgcn_global_load_lds((glb_ptr_t)(src + 1536 + lane),
                                     (lds_ptr_t)(&ldsW[wv][b][1536 + lane]),
                                     4, 0, 0);
  };

  float f[5][5];   // [chunk][patch]
  float s1[5] = {0.f, 0.f, 0.f, 0.f, 0.f};
  float s2[5] = {0.f, 0.f, 0.f, 0.f, 0.f};

  stage(0, 0);
  for (int k = 0; k < 5; ++k) {
    const int b = k & 1;
    if (k < 4) {
      stage(k + 1, b ^ 1);
      asm volatile("s_waitcnt vmcnt(7)" ::: "memory");
    } else {
      asm volatile("s_waitcnt vmcnt(0)" ::: "memory");
    }
    __builtin_amdgcn_sched_barrier(0);

    float w[25];
#pragma unroll
    for (int j = 0; j < 25; j++) w[j] = ldsW[wv][b][lane * 25 + j];

    float lt = 0.f, rt = 0.f, mid = 0.f, lb = 0.f, rb = 0.f;
#pragma unroll
    for (int a = 0; a < 3; a++)
#pragma unroll
      for (int c = 0; c < 3; c++) {
        lt += w[a * 5 + c];
        rt += w[(a + 2) * 5 + c];
        lb += w[a * 5 + (c + 2)];
        rb += w[(a + 2) * 5 + (c + 2)];
      }
#pragma unroll
    for (int a = 1; a < 5; a++)
#pragma unroll
      for (int c = 1; c < 5; c++) mid += w[a * 5 + c];
    f[k][0] = lt * (1.f / 9.f);
    f[k][1] = rt * (1.f / 9.f);
    f[k][2] = mid * (1.f / 16.f);
    f[k][3] = lb * (1.f / 9.f);
    f[k][4] = rb * (1.f / 9.f);
#pragma unroll
    for (int p = 0; p < 5; p++) {
      s1[p] += f[k][p];
      s2[p] = fmaf(f[k][p], f[k][p], s2[p]);
    }
    __builtin_amdgcn_sched_barrier(0);
  }

  // wave reduce (64 lanes)
#pragma unroll
  for (int off = 32; off > 0; off >>= 1)
#pragma unroll
    for (int p = 0; p < 5; p++) {
      s1[p] += __shfl_xor(s1[p], off);
      s2[p] += __shfl_xor(s2[p], off);
    }

  // pair reduce across the sample's two waves
  if (lane == 0) {
#pragma unroll
    for (int p = 0; p < 5; p++) { sred[wv][p] = s1[p]; sred[wv][5 + p] = s2[p]; }
  }
  __syncthreads();
  const int pw = wv ^ 1;
  float mu[5], rn[5], nrm[5];
#pragma unroll
  for (int p = 0; p < 5; p++) {
    float t1 = s1[p] + sred[pw][p];
    float t2 = s2[p] + sred[pw][5 + p];
    mu[p] = t1 * (1.0f / NC);
    float n2 = fmaxf(t2 - (float)NC * mu[p] * mu[p], 0.0f);
    nrm[p] = fmaxf(sqrtf(n2), 1e-8f);
    rn[p] = 1.0f / nrm[p];
  }

  if (lane == 0 && h == 0) {
    if (isQ) {
#pragma unroll
      for (int p = 0; p < 5; p++) {
        statsQ[(size_t)n * 10 + p] = mu[p];
        statsQ[(size_t)n * 10 + 5 + p] = nrm[p];
      }
    } else {
#pragma unroll
      for (int p = 0; p < 5; p++) {
        statsP[p * NW + n] = mu[p];
        statsP[(5 + p) * NW + n] = nrm[p];
      }
    }
  }

  // centered-normalized split-bf16 writes (coalesced: lane -> channel)
  u16* __restrict__ Oh = isQ ? Ah : Bh;
  u16* __restrict__ Ol = isQ ? Al : Bl;
#pragma unroll
  for (int p = 0; p < 5; p++) {
    const size_t rowb = ((size_t)n * 5 + p) * 640;
#pragma unroll
    for (int k = 0; k < 5; k++) {
      const int c = h * 320 + k * 64 + lane;
      float g = (f[k][p] - mu[p]) * rn[p];
      u16 hi = f2bf(g);
      float lo = g - bf2f(hi);
      Oh[rowb + c] = hi;
      Ol[rowb + c] = f2bf(lo);
    }
  }
}

// ---------------------------------------------------------------------------
// sim GEMM: C[10240][320] = A[10240][640] * Bt[320][640]^T, split-bf16 3-pass.
// Tile 128x64, BK=32, 4 waves (2x2), dbuf LDS, XOR-swizzled both sides,
// counted vmcnt(6). Epilogue -> packed f32. (Verified R5/R6.)
// ---------------------------------------------------------------------------
__global__ __launch_bounds__(256) void gemm_sim_kernel(const u16* __restrict__ Ah,
                                                       const u16* __restrict__ Al,
                                                       const u16* __restrict__ Bh,
                                                       const u16* __restrict__ Bl,
                                                       float* __restrict__ packed)
{
  __shared__ u16 ldsAh[2][128 * 32];
  __shared__ u16 ldsAl[2][128 * 32];
  __shared__ u16 ldsBh[2][64 * 32];
  __shared__ u16 ldsBl[2][64 * 32];
  const int bid = blockIdx.x;
  const int wg = (bid & 7) * 50 + (bid >> 3);  // bijective, 400 = 8*50
  const int bm = wg / 5;
  const int bn = wg % 5;
  const int row0 = bm * 128;
  const int col0 = bn * 64;
  const int tid = threadIdx.x;
  const int lane = tid & 63;
  const int w = tid >> 6;
  const int wr = w >> 1;
  const int wc = w & 1;

  f32x4 acc[4][2];
#pragma unroll
  for (int m = 0; m < 4; m++)
#pragma unroll
    for (int n = 0; n < 2; n++) acc[m][n] = (f32x4){0.f, 0.f, 0.f, 0.f};

  auto stage = [&](int kt, int b) {
    const int k0 = kt * 32;
#pragma unroll
    for (int i = 0; i < 2; i++) {
      const int s = tid + i * 256;
      const int r = s >> 2;
      const int chl = (s & 3) ^ ((r >> 1) & 3);
      const size_t go = (size_t)(row0 + r) * 640 + k0 + chl * 8;
      __builtin_amdgcn_global_load_lds((glb_ptr_t)(Ah + go),
                                       (lds_ptr_t)(&ldsAh[b][s * 8]), 16, 0, 0);
      __builtin_amdgcn_global_load_lds((glb_ptr_t)(Al + go),
                                       (lds_ptr_t)(&ldsAl[b][s * 8]), 16, 0, 0);
    }
    {
      const int r = tid >> 2;
      const int chl = (tid & 3) ^ ((r >> 1) & 3);
      const size_t go = (size_t)(col0 + r) * 640 + k0 + chl * 8;
      __builtin_amdgcn_global_load_lds((glb_ptr_t)(Bh + go),
                                       (lds_ptr_t)(&ldsBh[b][tid * 8]), 16, 0, 0);
      __builtin_amdgcn_global_load_lds((glb_ptr_t)(Bl + go),
                                       (lds_ptr_t)(&ldsBl[b][tid * 8]), 16, 0, 0);
    }
  };

  stage(0, 0);
  for (int kt = 0; kt < 20; ++kt) {
    const int b = kt & 1;
    if (kt < 19) {
      stage(kt + 1, b ^ 1);
      asm volatile("s_waitcnt vmcnt(6)" ::: "memory");
    } else {
      asm volatile("s_waitcnt vmcnt(0)" ::: "memory");
    }
    __builtin_amdgcn_sched_barrier(0);
    __builtin_amdgcn_s_barrier();

    const int rq = lane & 15;
    const int kq = lane >> 4;
    short8 ah[4], al[4], bh[2], bl[2];
#pragma unroll
    for (int m = 0; m < 4; m++) {
      const int row = wr * 64 + m * 16 + rq;
      const int off = row * 32 + ((kq ^ ((row >> 1) & 3)) * 8);
      ah[m] = *(const short8*)&ldsAh[b][off];
      al[m] = *(const short8*)&ldsAl[b][off];
    }
#pragma unroll
    for (int n = 0; n < 2; n++) {
      const int row = wc * 32 + n * 16 + rq;
      const int off = row * 32 + ((kq ^ ((row >> 1) & 3)) * 8);
      bh[n] = *(const short8*)&ldsBh[b][off];
      bl[n] = *(const short8*)&ldsBl[b][off];
    }
#pragma unroll
    for (int m = 0; m < 4; m++)
#pragma unroll
      for (int n = 0; n < 2; n++) {
        acc[m][n] = __builtin_amdgcn_mfma_f32_16x16x32_bf16(ah[m], bh[n], acc[m][n], 0, 0, 0);
        acc[m][n] = __builtin_amdgcn_mfma_f32_16x16x32_bf16(ah[m], bl[n], acc[m][n], 0, 0, 0);
        acc[m][n] = __builtin_amdgcn_mfma_f32_16x16x32_bf16(al[m], bh[n], acc[m][n], 0, 0, 0);
      }

    __builtin_amdgcn_sched_barrier(0);
    __builtin_amdgcn_s_barrier();
  }

#pragma unroll
  for (int m = 0; m < 4; m++)
#pragma unroll
    for (int n = 0; n < 2; n++)
#pragma unroll
      for (int r = 0; r < 4; r++) {
        const unsigned R = row0 + wr * 64 + m * 16 + (lane >> 4) * 4 + r;
        const unsigned Cc = col0 + wc * 32 + n * 16 + (lane & 15);
        const unsigned mq = R / 5u;
        const unsigned i = R - mq * 5u;
        const unsigned wp = Cc / 5u;
        const unsigned j = Cc - wp * 5u;
        packed[((size_t)mq * 64 + wp) * 32 + i * 5 + j] = acc[m][n][r];
      }
}

// ---------------------------------------------------------------------------
// Sinkhorn: thread <-> (m,w). dot reconstructed from sim diagonal + stats.
// ---------------------------------------------------------------------------
__global__ __launch_bounds__(256) void sink3_kernel(const float* __restrict__ packed,
                                                    const float* __restrict__ statsQ,
                                                    const float* __restrict__ statsP,
                                                    float* __restrict__ out)
{
  const int tid = threadIdx.x;
  const int lane = tid & 63;
  const int wv = tid >> 6;
  const int m = blockIdx.x * 4 + wv;
  const float* pb = packed + ((size_t)m * 64 + lane) * 32;

  float sm[25];
  {
    const f32x4* pv = (const f32x4*)pb;
#pragma unroll
    for (int q = 0; q < 6; q++) {
      f32x4 t = pv[q];
#pragma unroll
      for (int e = 0; e < 4; e++) sm[q * 4 + e] = t[e];
    }
    sm[24] = pb[24];
  }

  float dot[5];
#pragma unroll
  for (int p = 0; p < 5; p++) {
    float muq = statsQ[(size_t)m * 10 + p];
    float nq = statsQ[(size_t)m * 10 + 5 + p];
    float mup = statsP[p * NW + lane];
    float np = statsP[(5 + p) * NW + lane];
    dot[p] = sm[p * 5 + p] * (nq * np) + 640.0f * muq * mup;
  }

  out[(size_t)m * 64 + lane] = sinkhorn_core(sm, dot);
}

extern "C" void kernel_launch(void* const* d_in, const int* in_sizes, int n_in,
                              void* d_out, int out_size, void* d_ws, size_t ws_size,
                              hipStream_t stream) {
  const float* proto = (const float*)d_in[0];  // (1,64,640,5,5)
  const float* query = (const float*)d_in[1];  // (2048,640,5,5)
  float* out = (float*)d_out;                  // (2048,64) f32

  const size_t nA = (size_t)NQ * 5 * NC;   // 6,553,600 u16
  const size_t nB = (size_t)NW * 5 * NC;   // 204,800 u16
  u16* Ah = (u16*)d_ws;
  u16* Al = Ah + nA;
  u16* Bh = Al + nA;
  u16* Bl = Bh + nB;
  float* statsQ = (float*)(Bl + nB);
  float* statsP = statsQ + (size_t)NQ * 10;
  float* packed = statsP + 10 * NW;

  feat_kernel<<<1056, 256, 0, stream>>>(query, proto, Ah, Al, Bh, Bl, statsQ, statsP);
  gemm_sim_kernel<<<400, 256, 0, stream>>>(Ah, Al, Bh, Bl, packed);
  sink3_kernel<<<NQ / 4, 256, 0, stream>>>(packed, statsQ, statsP, out);
}